// Round 6
// baseline (537.621 us; speedup 1.0000x reference)
//
#include <hip/hip_runtime.h>

#define NB 8
#define NC 192
#define HEADS 6
#define CHH 32
#define IMH 128
#define IMW 128
#define NHW (IMH*IMW)
#define EPSN 1e-12f
#define NBCHW (NB*NC*NHW)   // 25165824

typedef _Float16 half8 __attribute__((ext_vector_type(8)));
typedef __attribute__((ext_vector_type(4))) float floatx4;
typedef unsigned short ushort_t;

#define MFMA_F16(a,b,c) __builtin_amdgcn_mfma_f32_16x16x32_f16(a,b,c,0,0,0)

// pack 2 floats to fp16 pair (RNE)
__device__ __forceinline__ unsigned pk2(float a, float b){
  union { _Float16 h[2]; unsigned u; } x;
  x.h[0] = (_Float16)a; x.h[1] = (_Float16)b; return x.u;
}
// split 2 floats into fp16 (hi, lo) pairs
__device__ __forceinline__ void pksplit(float a, float b, unsigned& hi, unsigned& lo){
  _Float16 ha = (_Float16)a, hb = (_Float16)b;
  float ra = a - (float)ha, rb = b - (float)hb;
  union { _Float16 h[2]; unsigned u; } x;
  x.h[0] = ha; x.h[1] = hb; hi = x.u;
  x.h[0] = (_Float16)ra; x.h[1] = (_Float16)rb; lo = x.u;
}

// LDS plane offsets (u32 units); row stride 36 u32 (= 72 fp16), 32 rows
#define PLN 1152          // 32*36
#define QH 0
#define QL (1*PLN)
#define KH (2*PLN)
#define KL (3*PLN)
#define VV (4*PLN)

// ---------------------------------------------------------------------------
// K1: dwconv(q,k,v) + fp16-split MFMA gram partials + norm partials.
// V transposed via LDS, stored single-fp16 PRE-PACKED in k3 B-frag order.
// block = (b,head) x 8-row slab; inner loop = 16 half-rows (64 px).
// ---------------------------------------------------------------------------
__global__ __launch_bounds__(256, 4) void k1_conv_gram(
    const float* __restrict__ x,
    const float* __restrict__ wq, const float* __restrict__ bq,
    const float* __restrict__ wk, const float* __restrict__ bk,
    const float* __restrict__ wv, const float* __restrict__ bv,
    ushort_t* __restrict__ vout,
    float* __restrict__ qn, float* __restrict__ kn,
    float* __restrict__ attn)
{
  __shared__ unsigned sm[5*PLN];   // 23040 B
  const int t  = threadIdx.x;
  const int b  = blockIdx.x / HEADS;
  const int h  = blockIdx.x % HEADS;
  const int r0 = blockIdx.y * 8;
  const int c  = t >> 3;           // channel 0..31
  const int s  = t & 7;            // 8-px strip within half
  const int cg = h*CHH + c;
  const float* xplane = x + (size_t)(b*NC + cg)*NHW;

  float wqr[9], wkr[9], wvr[9];
#pragma unroll
  for (int m = 0; m < 9; ++m) {
    wqr[m] = wq[cg*9+m]; wkr[m] = wk[cg*9+m]; wvr[m] = wv[cg*9+m];
  }
  const float bqv = bq[cg], bkv = bk[cg], bvv = bv[cg];

  const int lane = t & 63;
  const int wid  = t >> 6;         // wave id
  const int gsel = lane >> 4, l15 = lane & 15;
  const int oct  = wid;            // transpose: this wave's channel octet

  floatx4 acc[2][2];
#pragma unroll
  for (int mt = 0; mt < 2; ++mt)
#pragma unroll
    for (int nt = 0; nt < 2; ++nt) acc[mt][nt] = (floatx4){0.f,0.f,0.f,0.f};
  float qnacc = 0.f, knacc = 0.f;

  for (int r = r0; r < r0 + 8; ++r) {
#pragma unroll
    for (int half = 0; half < 2; ++half) {
      const int px0 = half*64 + s*8;
      // ---- conv: 8 px ----
      float xr[3][10];
#pragma unroll
      for (int dr = 0; dr < 3; ++dr) {
        const int rr = r - 1 + dr;
        if (rr >= 0 && rr < IMH) {
          const float* rp = xplane + rr*IMW;
          xr[dr][0] = (px0 > 0) ? rp[px0-1] : 0.f;
          const float4 f0 = *(const float4*)(rp + px0);
          const float4 f1 = *(const float4*)(rp + px0 + 4);
          xr[dr][1]=f0.x; xr[dr][2]=f0.y; xr[dr][3]=f0.z; xr[dr][4]=f0.w;
          xr[dr][5]=f1.x; xr[dr][6]=f1.y; xr[dr][7]=f1.z; xr[dr][8]=f1.w;
          xr[dr][9] = (px0 + 8 < IMW) ? rp[px0+8] : 0.f;
        } else {
#pragma unroll
          for (int j = 0; j < 10; ++j) xr[dr][j] = 0.f;
        }
      }
      float qv[8], kv[8], vv8[8];
#pragma unroll
      for (int p = 0; p < 8; ++p) {
        float qa = bqv, ka = bkv, va = bvv;
#pragma unroll
        for (int dy = 0; dy < 3; ++dy)
#pragma unroll
          for (int dx = 0; dx < 3; ++dx) {
            const float xv = xr[dy][p+dx];
            qa = fmaf(wqr[dy*3+dx], xv, qa);
            ka = fmaf(wkr[dy*3+dx], xv, ka);
            va = fmaf(wvr[dy*3+dx], xv, va);
          }
        qnacc = fmaf(qa, qa, qnacc);
        knacc = fmaf(ka, ka, knacc);
        qv[p] = qa; kv[p] = ka; vv8[p] = va;
      }
      // ---- split/pack -> LDS (row c, u32 cols s*4..s*4+3) ----
      unsigned qhp[4], qlp[4], khp[4], klp[4], vvp[4];
#pragma unroll
      for (int j = 0; j < 4; ++j) {
        pksplit(qv[2*j], qv[2*j+1], qhp[j], qlp[j]);
        pksplit(kv[2*j], kv[2*j+1], khp[j], klp[j]);
        vvp[j] = pk2(vv8[2*j], vv8[2*j+1]);
      }
      const int wb = c*36 + s*4;
      *(uint4*)&sm[QH + wb] = make_uint4(qhp[0],qhp[1],qhp[2],qhp[3]);
      *(uint4*)&sm[QL + wb] = make_uint4(qlp[0],qlp[1],qlp[2],qlp[3]);
      *(uint4*)&sm[KH + wb] = make_uint4(khp[0],khp[1],khp[2],khp[3]);
      *(uint4*)&sm[KL + wb] = make_uint4(klp[0],klp[1],klp[2],klp[3]);
      *(uint4*)&sm[VV + wb] = make_uint4(vvp[0],vvp[1],vvp[2],vvp[3]);
      __syncthreads();

      // ---- v transpose: wave=oct, px=lane; pack channel pairs ----
      {
        const int px = lane;
        const int ph = px >> 1, sel = (px & 1) * 16;
        unsigned w4[4];
#pragma unroll
        for (int i2 = 0; i2 < 4; ++i2) {
          const unsigned ua = sm[VV + (oct*8 + 2*i2    )*36 + ph];
          const unsigned ub = sm[VV + (oct*8 + 2*i2 + 1)*36 + ph];
          w4[i2] = ((ua >> sel) & 0xffffu) | (((ub >> sel) & 0xffffu) << 16);
        }
        const size_t tile = ((size_t)b*1024 + (size_t)r*8 + half*4 + (px>>4))*6 + h;
        ushort_t* dst = vout + tile*512 + (size_t)(oct*16 + (px&15))*8;
        *(uint4*)dst = make_uint4(w4[0],w4[1],w4[2],w4[3]);
      }
      // ---- gram: waves {0,1}<->half0, {2,3}<->half1; K=32 MFMA, zero VALU ----
      if ((wid >> 1) == half) {
        const int col = (wid & 1)*16 + gsel*4;
        half8 aqh[2], aql[2], akh[2], akl[2];
#pragma unroll
        for (int mt = 0; mt < 2; ++mt) {
          const int row = (mt*16 + l15)*36 + col;
          aqh[mt] = *(const half8*)&sm[QH + row];
          aql[mt] = *(const half8*)&sm[QL + row];
          akh[mt] = *(const half8*)&sm[KH + row];
          akl[mt] = *(const half8*)&sm[KL + row];
        }
#pragma unroll
        for (int mt = 0; mt < 2; ++mt)
#pragma unroll
          for (int nt = 0; nt < 2; ++nt) {
            acc[mt][nt] = MFMA_F16(aqh[mt], akh[nt], acc[mt][nt]);
            acc[mt][nt] = MFMA_F16(aqh[mt], akl[nt], acc[mt][nt]);
            acc[mt][nt] = MFMA_F16(aql[mt], akh[nt], acc[mt][nt]);
          }
      }
      __syncthreads();
    }
  }

  // ---- norm partials (8 strip lanes contiguous) ----
  qnacc += __shfl_xor(qnacc, 1); qnacc += __shfl_xor(qnacc, 2); qnacc += __shfl_xor(qnacc, 4);
  knacc += __shfl_xor(knacc, 1); knacc += __shfl_xor(knacc, 2); knacc += __shfl_xor(knacc, 4);
  if (s == 0) {
    atomicAdd(qn + b*NC + cg, qnacc);
    atomicAdd(kn + b*NC + cg, knacc);
  }

  // ---- gram partials: 4-wave LDS reduce, then atomics ----
  float* red = (float*)sm;   // 16 KB <= 23 KB
#pragma unroll
  for (int mt = 0; mt < 2; ++mt)
#pragma unroll
    for (int nt = 0; nt < 2; ++nt)
#pragma unroll
      for (int rg = 0; rg < 4; ++rg)
        red[wid*1024 + (mt*2+nt)*256 + lane*4 + rg] = acc[mt][nt][rg];
  __syncthreads();
  float* abuf = attn + (b*HEADS + h)*(CHH*CHH);
#pragma unroll
  for (int e = 0; e < 4; ++e) {
    const int idx = e*256 + t;
    const float sum = red[idx] + red[1024+idx] + red[2048+idx] + red[3072+idx];
    const int tile = idx >> 8;
    const int ln   = (idx >> 2) & 63;
    const int rg   = idx & 3;
    const int cc   = (tile>>1)*16 + (ln>>4)*4 + rg;
    const int dd   = (tile&1)*16 + (ln & 15);
    atomicAdd(abuf + cc*CHH + dd, sum);
  }
}

// ---------------------------------------------------------------------------
// K2: normalize, softmax, fold projection; M pre-packed fp16 hi/lo A-frags.
// ---------------------------------------------------------------------------
__global__ __launch_bounds__(256) void k2_softmax_M(
    const float* __restrict__ wp,
    const float* __restrict__ qn, const float* __restrict__ kn,
    const float* __restrict__ attn,
    half8* __restrict__ mhi, half8* __restrict__ mlo)
{
  __shared__ float a[CHH][CHH+1];
  __shared__ float qs[CHH], ks_[CHH];
  const int t = threadIdx.x;
  const int b = blockIdx.x / HEADS;
  const int h = blockIdx.x % HEADS;
  const float* raw = attn + (b*HEADS + h)*(CHH*CHH);
  if (t < CHH) {
    qs[t]  = fmaxf(sqrtf(qn[b*NC + h*CHH + t]), EPSN);
    ks_[t] = fmaxf(sqrtf(kn[b*NC + h*CHH + t]), EPSN);
  }
  __syncthreads();
#pragma unroll
  for (int rep = 0; rep < 4; ++rep) {
    const int idx = rep*256 + t;
    const int cc = idx >> 5, dd = idx & 31;
    a[cc][dd] = raw[idx] / (qs[cc] * ks_[dd]);
  }
  __syncthreads();
  if (t < CHH) {
    float m = -1e30f;
    for (int d = 0; d < CHH; ++d) m = fmaxf(m, a[t][d]);
    float sum = 0.f;
    for (int d = 0; d < CHH; ++d) { const float e = expf(a[t][d] - m); a[t][d] = e; sum += e; }
    const float inv = 1.f / sum;
    for (int d = 0; d < CHH; ++d) a[t][d] *= inv;
  }
  __syncthreads();
#pragma unroll
  for (int rep = 0; rep < 3; ++rep) {
    const int slot = rep*256 + t;
    const int o = slot >> 2;
    const int g = slot & 3;
    float m[8];
#pragma unroll
    for (int i = 0; i < 8; ++i) m[i] = 0.f;
    for (int cp = 0; cp < CHH; ++cp) {
      const float w = wp[o*NC + h*CHH + cp];
#pragma unroll
      for (int i = 0; i < 8; ++i) m[i] = fmaf(w, a[cp][g*8+i], m[i]);
    }
    half8 hi8, lo8;
#pragma unroll
    for (int i = 0; i < 8; ++i) {
      const _Float16 hh = (_Float16)m[i];
      hi8[i] = hh;
      lo8[i] = (_Float16)(m[i] - (float)hh);
    }
    const size_t mi = (((size_t)b*12 + (o>>4))*6 + h)*64 + g*16 + (o&15);
    mhi[mi] = hi8; mlo[mi] = lo8;
  }
}

// ---------------------------------------------------------------------------
// K3: out = M·V + bp. fp16 MFMA, 2-product (Mhi+Mlo)·V. All frags coalesced.
// block = 128 px x 192 o; wave = 64 px (4 tiles) x 96 o (6 tiles).
// ---------------------------------------------------------------------------
__global__ __launch_bounds__(256) void k3_gemm(
    const half8* __restrict__ v,
    const half8* __restrict__ mhi, const half8* __restrict__ mlo,
    const float* __restrict__ bp, float* __restrict__ out)
{
  const int t    = threadIdx.x;
  const int b    = blockIdx.y;
  const int lane = t & 63;
  const int w    = t >> 6;
  const int whw  = w & 1;
  const int wo   = w >> 1;
  const int ht0  = blockIdx.x*8 + whw*4;
  const int ot0  = wo*6;
  const int gsel = lane >> 4, l15 = lane & 15;

  floatx4 acc[6][4];
#pragma unroll
  for (int ot = 0; ot < 6; ++ot)
#pragma unroll
    for (int nt = 0; nt < 4; ++nt) acc[ot][nt] = (floatx4){0.f,0.f,0.f,0.f};

  const size_t vbase = ((size_t)b*1024 + ht0)*6;
  const size_t mbase = ((size_t)b*12 + ot0)*6;
#pragma unroll
  for (int ks = 0; ks < 6; ++ks) {
    half8 bf[4];
#pragma unroll
    for (int nt = 0; nt < 4; ++nt)
      bf[nt] = v[(vbase + (size_t)nt*6 + ks)*64 + lane];
#pragma unroll
    for (int ot = 0; ot < 6; ++ot) {
      const size_t mi = (mbase + (size_t)ot*6 + ks)*64 + lane;
      const half8 ah = mhi[mi];
      const half8 al = mlo[mi];
#pragma unroll
      for (int nt = 0; nt < 4; ++nt) {
        acc[ot][nt] = MFMA_F16(ah, bf[nt], acc[ot][nt]);
        acc[ot][nt] = MFMA_F16(al, bf[nt], acc[ot][nt]);
      }
    }
  }
#pragma unroll
  for (int ot = 0; ot < 6; ++ot) {
#pragma unroll
    for (int rg = 0; rg < 4; ++rg) {
      const int o = (ot0 + ot)*16 + gsel*4 + rg;
      const float bpv = bp[o];
#pragma unroll
      for (int nt = 0; nt < 4; ++nt) {
        const int hw = (ht0 + nt)*16 + l15;
        out[((size_t)(b*NC + o))*NHW + hw] = acc[ot][nt][rg] + bpv;
      }
    }
  }
}

extern "C" void kernel_launch(void* const* d_in, const int* in_sizes, int n_in,
                              void* d_out, int out_size, void* d_ws, size_t ws_size,
                              hipStream_t stream)
{
  const float* x  = (const float*)d_in[0];
  const float* wq = (const float*)d_in[1];
  const float* bq = (const float*)d_in[2];
  const float* wk = (const float*)d_in[3];
  const float* bk = (const float*)d_in[4];
  const float* wv = (const float*)d_in[5];
  const float* bv = (const float*)d_in[6];
  const float* wp = (const float*)d_in[7];
  const float* bp = (const float*)d_in[8];
  float* out = (float*)d_out;

  // workspace layout
  ushort_t* vout = (ushort_t*)d_ws;                       // fp16 V frags
  float* fbase   = (float*)(vout + (size_t)NBCHW);
  float* qn      = fbase;
  float* kn      = qn + NB*NC;
  float* attn    = kn + NB*NC;
  half8* mhi     = (half8*)(attn + NB*HEADS*CHH*CHH);
  half8* mlo     = mhi + (size_t)NB*12*6*64;

  hipMemsetAsync(fbase, 0,
                 (size_t)(2*NB*NC + NB*HEADS*CHH*CHH)*sizeof(float), stream);

  k1_conv_gram<<<dim3(NB*HEADS, 16), 256, 0, stream>>>(
      x, wq, bq, wk, bk, wv, bv, vout, qn, kn, attn);
  k2_softmax_M<<<NB*HEADS, 256, 0, stream>>>(wp, qn, kn, attn, mhi, mlo);
  k3_gemm<<<dim3(NHW/128, NB), 256, 0, stream>>>(
      (const half8*)vout, mhi, mlo, bp, out);
}

// Round 7
// 290.371 us; speedup vs baseline: 1.8515x; 1.8515x over previous
//
#include <hip/hip_runtime.h>

#define NB 8
#define NC 192
#define HEADS 6
#define CHH 32
#define IMH 128
#define IMW 128
#define NHW (IMH*IMW)
#define EPSN 1e-12f
#define NBCHW (NB*NC*NHW)   // 25165824

typedef _Float16 half8 __attribute__((ext_vector_type(8)));
typedef __attribute__((ext_vector_type(4))) float floatx4;
typedef unsigned short ushort_t;

#define MFMA_F16(a,b,c) __builtin_amdgcn_mfma_f32_16x16x32_f16(a,b,c,0,0,0)

// pack 2 floats to fp16 pair (RNE)
__device__ __forceinline__ unsigned pk2(float a, float b){
  union { _Float16 h[2]; unsigned u; } x;
  x.h[0] = (_Float16)a; x.h[1] = (_Float16)b; return x.u;
}
// split 2 floats into fp16 (hi, lo) pairs
__device__ __forceinline__ void pksplit(float a, float b, unsigned& hi, unsigned& lo){
  _Float16 ha = (_Float16)a, hb = (_Float16)b;
  float ra = a - (float)ha, rb = b - (float)hb;
  union { _Float16 h[2]; unsigned u; } x;
  x.h[0] = ha; x.h[1] = hb; hi = x.u;
  x.h[0] = (_Float16)ra; x.h[1] = (_Float16)rb; lo = x.u;
}

// LDS plane offsets (u32 units); row stride 36 u32 (= 72 fp16), 32 rows
#define PLN 1152          // 32*36
#define QH 0
#define QL (1*PLN)
#define KH (2*PLN)
#define KL (3*PLN)
#define VV (4*PLN)

// ---------------------------------------------------------------------------
// K1: dwconv(q,k,v) + fp16-split MFMA gram partials + norm partials.
// V transposed via LDS, stored single-fp16 PRE-PACKED in k3 B-frag order.
// block = (b,head) x 8-row slab; inner loop = 16 half-rows (64 px).
// NOTE: plain launch_bounds — (256,4) capped VGPR at 64 and spilled the conv
// arrays to scratch (R6: FETCH 929 MB vs 125 logical, VALUBusy 8%).
// ---------------------------------------------------------------------------
__global__ __launch_bounds__(256) void k1_conv_gram(
    const float* __restrict__ x,
    const float* __restrict__ wq, const float* __restrict__ bq,
    const float* __restrict__ wk, const float* __restrict__ bk,
    const float* __restrict__ wv, const float* __restrict__ bv,
    ushort_t* __restrict__ vout,
    float* __restrict__ qn, float* __restrict__ kn,
    float* __restrict__ attn)
{
  __shared__ unsigned sm[5*PLN];   // 23040 B
  const int t  = threadIdx.x;
  const int b  = blockIdx.x / HEADS;
  const int h  = blockIdx.x % HEADS;
  const int r0 = blockIdx.y * 8;
  const int c  = t >> 3;           // channel 0..31
  const int s  = t & 7;            // 8-px strip within half
  const int cg = h*CHH + c;
  const float* xplane = x + (size_t)(b*NC + cg)*NHW;

  float wqr[9], wkr[9], wvr[9];
#pragma unroll
  for (int m = 0; m < 9; ++m) {
    wqr[m] = wq[cg*9+m]; wkr[m] = wk[cg*9+m]; wvr[m] = wv[cg*9+m];
  }
  const float bqv = bq[cg], bkv = bk[cg], bvv = bv[cg];

  const int lane = t & 63;
  const int wid  = t >> 6;         // wave id
  const int gsel = lane >> 4, l15 = lane & 15;
  const int oct  = wid;            // transpose: this wave's channel octet

  floatx4 acc[2][2];
#pragma unroll
  for (int mt = 0; mt < 2; ++mt)
#pragma unroll
    for (int nt = 0; nt < 2; ++nt) acc[mt][nt] = (floatx4){0.f,0.f,0.f,0.f};
  float qnacc = 0.f, knacc = 0.f;

  for (int r = r0; r < r0 + 8; ++r) {
#pragma unroll
    for (int half = 0; half < 2; ++half) {
      const int px0 = half*64 + s*8;
      // ---- conv: 8 px ----
      float xr[3][10];
#pragma unroll
      for (int dr = 0; dr < 3; ++dr) {
        const int rr = r - 1 + dr;
        if (rr >= 0 && rr < IMH) {
          const float* rp = xplane + rr*IMW;
          xr[dr][0] = (px0 > 0) ? rp[px0-1] : 0.f;
          const float4 f0 = *(const float4*)(rp + px0);
          const float4 f1 = *(const float4*)(rp + px0 + 4);
          xr[dr][1]=f0.x; xr[dr][2]=f0.y; xr[dr][3]=f0.z; xr[dr][4]=f0.w;
          xr[dr][5]=f1.x; xr[dr][6]=f1.y; xr[dr][7]=f1.z; xr[dr][8]=f1.w;
          xr[dr][9] = (px0 + 8 < IMW) ? rp[px0+8] : 0.f;
        } else {
#pragma unroll
          for (int j = 0; j < 10; ++j) xr[dr][j] = 0.f;
        }
      }
      float qv[8], kv[8], vv8[8];
#pragma unroll
      for (int p = 0; p < 8; ++p) {
        float qa = bqv, ka = bkv, va = bvv;
#pragma unroll
        for (int dy = 0; dy < 3; ++dy)
#pragma unroll
          for (int dx = 0; dx < 3; ++dx) {
            const float xv = xr[dy][p+dx];
            qa = fmaf(wqr[dy*3+dx], xv, qa);
            ka = fmaf(wkr[dy*3+dx], xv, ka);
            va = fmaf(wvr[dy*3+dx], xv, va);
          }
        qnacc = fmaf(qa, qa, qnacc);
        knacc = fmaf(ka, ka, knacc);
        qv[p] = qa; kv[p] = ka; vv8[p] = va;
      }
      // ---- split/pack -> LDS (row c, u32 cols s*4..s*4+3) ----
      unsigned qhp[4], qlp[4], khp[4], klp[4], vvp[4];
#pragma unroll
      for (int j = 0; j < 4; ++j) {
        pksplit(qv[2*j], qv[2*j+1], qhp[j], qlp[j]);
        pksplit(kv[2*j], kv[2*j+1], khp[j], klp[j]);
        vvp[j] = pk2(vv8[2*j], vv8[2*j+1]);
      }
      const int wb = c*36 + s*4;
      *(uint4*)&sm[QH + wb] = make_uint4(qhp[0],qhp[1],qhp[2],qhp[3]);
      *(uint4*)&sm[QL + wb] = make_uint4(qlp[0],qlp[1],qlp[2],qlp[3]);
      *(uint4*)&sm[KH + wb] = make_uint4(khp[0],khp[1],khp[2],khp[3]);
      *(uint4*)&sm[KL + wb] = make_uint4(klp[0],klp[1],klp[2],klp[3]);
      *(uint4*)&sm[VV + wb] = make_uint4(vvp[0],vvp[1],vvp[2],vvp[3]);
      __syncthreads();

      // ---- v transpose: wave=oct, px=lane; pack channel pairs ----
      {
        const int px = lane;
        const int ph = px >> 1, sel = (px & 1) * 16;
        unsigned w4[4];
#pragma unroll
        for (int i2 = 0; i2 < 4; ++i2) {
          const unsigned ua = sm[VV + (oct*8 + 2*i2    )*36 + ph];
          const unsigned ub = sm[VV + (oct*8 + 2*i2 + 1)*36 + ph];
          w4[i2] = ((ua >> sel) & 0xffffu) | (((ub >> sel) & 0xffffu) << 16);
        }
        const size_t tile = ((size_t)b*1024 + (size_t)r*8 + half*4 + (px>>4))*6 + h;
        ushort_t* dst = vout + tile*512 + (size_t)(oct*16 + (px&15))*8;
        *(uint4*)dst = make_uint4(w4[0],w4[1],w4[2],w4[3]);
      }
      // ---- gram: waves {0,1}<->half0, {2,3}<->half1; K=32 MFMA, zero VALU ----
      if ((wid >> 1) == half) {
        const int col = (wid & 1)*16 + gsel*4;
        half8 aqh[2], aql[2], akh[2], akl[2];
#pragma unroll
        for (int mt = 0; mt < 2; ++mt) {
          const int row = (mt*16 + l15)*36 + col;
          aqh[mt] = *(const half8*)&sm[QH + row];
          aql[mt] = *(const half8*)&sm[QL + row];
          akh[mt] = *(const half8*)&sm[KH + row];
          akl[mt] = *(const half8*)&sm[KL + row];
        }
#pragma unroll
        for (int mt = 0; mt < 2; ++mt)
#pragma unroll
          for (int nt = 0; nt < 2; ++nt) {
            acc[mt][nt] = MFMA_F16(aqh[mt], akh[nt], acc[mt][nt]);
            acc[mt][nt] = MFMA_F16(aqh[mt], akl[nt], acc[mt][nt]);
            acc[mt][nt] = MFMA_F16(aql[mt], akh[nt], acc[mt][nt]);
          }
      }
      __syncthreads();
    }
  }

  // ---- norm partials (8 strip lanes contiguous) ----
  qnacc += __shfl_xor(qnacc, 1); qnacc += __shfl_xor(qnacc, 2); qnacc += __shfl_xor(qnacc, 4);
  knacc += __shfl_xor(knacc, 1); knacc += __shfl_xor(knacc, 2); knacc += __shfl_xor(knacc, 4);
  if (s == 0) {
    atomicAdd(qn + b*NC + cg, qnacc);
    atomicAdd(kn + b*NC + cg, knacc);
  }

  // ---- gram partials: 4-wave LDS reduce, then atomics ----
  float* red = (float*)sm;   // 16 KB <= 23 KB
#pragma unroll
  for (int mt = 0; mt < 2; ++mt)
#pragma unroll
    for (int nt = 0; nt < 2; ++nt)
#pragma unroll
      for (int rg = 0; rg < 4; ++rg)
        red[wid*1024 + (mt*2+nt)*256 + lane*4 + rg] = acc[mt][nt][rg];
  __syncthreads();
  float* abuf = attn + (b*HEADS + h)*(CHH*CHH);
#pragma unroll
  for (int e = 0; e < 4; ++e) {
    const int idx = e*256 + t;
    const float sum = red[idx] + red[1024+idx] + red[2048+idx] + red[3072+idx];
    const int tile = idx >> 8;
    const int ln   = (idx >> 2) & 63;
    const int rg   = idx & 3;
    const int cc   = (tile>>1)*16 + (ln>>4)*4 + rg;
    const int dd   = (tile&1)*16 + (ln & 15);
    atomicAdd(abuf + cc*CHH + dd, sum);
  }
}

// ---------------------------------------------------------------------------
// K2: normalize, softmax, fold projection; M pre-packed fp16 hi/lo A-frags.
// ---------------------------------------------------------------------------
__global__ __launch_bounds__(256) void k2_softmax_M(
    const float* __restrict__ wp,
    const float* __restrict__ qn, const float* __restrict__ kn,
    const float* __restrict__ attn,
    half8* __restrict__ mhi, half8* __restrict__ mlo)
{
  __shared__ float a[CHH][CHH+1];
  __shared__ float qs[CHH], ks_[CHH];
  const int t = threadIdx.x;
  const int b = blockIdx.x / HEADS;
  const int h = blockIdx.x % HEADS;
  const float* raw = attn + (b*HEADS + h)*(CHH*CHH);
  if (t < CHH) {
    qs[t]  = fmaxf(sqrtf(qn[b*NC + h*CHH + t]), EPSN);
    ks_[t] = fmaxf(sqrtf(kn[b*NC + h*CHH + t]), EPSN);
  }
  __syncthreads();
#pragma unroll
  for (int rep = 0; rep < 4; ++rep) {
    const int idx = rep*256 + t;
    const int cc = idx >> 5, dd = idx & 31;
    a[cc][dd] = raw[idx] / (qs[cc] * ks_[dd]);
  }
  __syncthreads();
  if (t < CHH) {
    float m = -1e30f;
    for (int d = 0; d < CHH; ++d) m = fmaxf(m, a[t][d]);
    float sum = 0.f;
    for (int d = 0; d < CHH; ++d) { const float e = expf(a[t][d] - m); a[t][d] = e; sum += e; }
    const float inv = 1.f / sum;
    for (int d = 0; d < CHH; ++d) a[t][d] *= inv;
  }
  __syncthreads();
#pragma unroll
  for (int rep = 0; rep < 3; ++rep) {
    const int slot = rep*256 + t;
    const int o = slot >> 2;
    const int g = slot & 3;
    float m[8];
#pragma unroll
    for (int i = 0; i < 8; ++i) m[i] = 0.f;
    for (int cp = 0; cp < CHH; ++cp) {
      const float w = wp[o*NC + h*CHH + cp];
#pragma unroll
      for (int i = 0; i < 8; ++i) m[i] = fmaf(w, a[cp][g*8+i], m[i]);
    }
    half8 hi8, lo8;
#pragma unroll
    for (int i = 0; i < 8; ++i) {
      const _Float16 hh = (_Float16)m[i];
      hi8[i] = hh;
      lo8[i] = (_Float16)(m[i] - (float)hh);
    }
    const size_t mi = (((size_t)b*12 + (o>>4))*6 + h)*64 + g*16 + (o&15);
    mhi[mi] = hi8; mlo[mi] = lo8;
  }
}

// ---------------------------------------------------------------------------
// K3: out = M·V + bp. fp16 MFMA, 2-product (Mhi+Mlo)·V. All frags coalesced.
// block = 128 px x 192 o; wave = 64 px (4 tiles) x 96 o (6 tiles).
// ---------------------------------------------------------------------------
__global__ __launch_bounds__(256) void k3_gemm(
    const half8* __restrict__ v,
    const half8* __restrict__ mhi, const half8* __restrict__ mlo,
    const float* __restrict__ bp, float* __restrict__ out)
{
  const int t    = threadIdx.x;
  const int b    = blockIdx.y;
  const int lane = t & 63;
  const int w    = t >> 6;
  const int whw  = w & 1;
  const int wo   = w >> 1;
  const int ht0  = blockIdx.x*8 + whw*4;
  const int ot0  = wo*6;
  const int gsel = lane >> 4, l15 = lane & 15;

  floatx4 acc[6][4];
#pragma unroll
  for (int ot = 0; ot < 6; ++ot)
#pragma unroll
    for (int nt = 0; nt < 4; ++nt) acc[ot][nt] = (floatx4){0.f,0.f,0.f,0.f};

  const size_t vbase = ((size_t)b*1024 + ht0)*6;
  const size_t mbase = ((size_t)b*12 + ot0)*6;
#pragma unroll
  for (int ks = 0; ks < 6; ++ks) {
    half8 bf[4];
#pragma unroll
    for (int nt = 0; nt < 4; ++nt)
      bf[nt] = v[(vbase + (size_t)nt*6 + ks)*64 + lane];
#pragma unroll
    for (int ot = 0; ot < 6; ++ot) {
      const size_t mi = (mbase + (size_t)ot*6 + ks)*64 + lane;
      const half8 ah = mhi[mi];
      const half8 al = mlo[mi];
#pragma unroll
      for (int nt = 0; nt < 4; ++nt) {
        acc[ot][nt] = MFMA_F16(ah, bf[nt], acc[ot][nt]);
        acc[ot][nt] = MFMA_F16(al, bf[nt], acc[ot][nt]);
      }
    }
  }
#pragma unroll
  for (int ot = 0; ot < 6; ++ot) {
#pragma unroll
    for (int rg = 0; rg < 4; ++rg) {
      const int o = (ot0 + ot)*16 + gsel*4 + rg;
      const float bpv = bp[o];
#pragma unroll
      for (int nt = 0; nt < 4; ++nt) {
        const int hw = (ht0 + nt)*16 + l15;
        out[((size_t)(b*NC + o))*NHW + hw] = acc[ot][nt][rg] + bpv;
      }
    }
  }
}

extern "C" void kernel_launch(void* const* d_in, const int* in_sizes, int n_in,
                              void* d_out, int out_size, void* d_ws, size_t ws_size,
                              hipStream_t stream)
{
  const float* x  = (const float*)d_in[0];
  const float* wq = (const float*)d_in[1];
  const float* bq = (const float*)d_in[2];
  const float* wk = (const float*)d_in[3];
  const float* bk = (const float*)d_in[4];
  const float* wv = (const float*)d_in[5];
  const float* bv = (const float*)d_in[6];
  const float* wp = (const float*)d_in[7];
  const float* bp = (const float*)d_in[8];
  float* out = (float*)d_out;

  // workspace layout
  ushort_t* vout = (ushort_t*)d_ws;                       // fp16 V frags
  float* fbase   = (float*)(vout + (size_t)NBCHW);
  float* qn      = fbase;
  float* kn      = qn + NB*NC;
  float* attn    = kn + NB*NC;
  half8* mhi     = (half8*)(attn + NB*HEADS*CHH*CHH);
  half8* mlo     = mhi + (size_t)NB*12*6*64;

  hipMemsetAsync(fbase, 0,
                 (size_t)(2*NB*NC + NB*HEADS*CHH*CHH)*sizeof(float), stream);

  k1_conv_gram<<<dim3(NB*HEADS, 16), 256, 0, stream>>>(
      x, wq, bq, wk, bk, wv, bv, vout, qn, kn, attn);
  k2_softmax_M<<<NB*HEADS, 256, 0, stream>>>(wp, qn, kn, attn, mhi, mlo);
  k3_gemm<<<dim3(NHW/128, NB), 256, 0, stream>>>(
      (const half8*)vout, mhi, mlo, bp, out);
}

// Round 9
// 283.457 us; speedup vs baseline: 1.8967x; 1.0244x over previous
//
#include <hip/hip_runtime.h>

#define NB 8
#define NC 192
#define HEADS 6
#define CHH 32
#define IMH 128
#define IMW 128
#define NHW (IMH*IMW)
#define EPSN 1e-12f
#define NBCHW (NB*NC*NHW)   // 25165824

typedef _Float16 half8 __attribute__((ext_vector_type(8)));
typedef __attribute__((ext_vector_type(4))) float floatx4;
typedef unsigned short ushort_t;

#define MFMA_F16(a,b,c) __builtin_amdgcn_mfma_f32_16x16x32_f16(a,b,c,0,0,0)

// pack 2 floats to fp16 pair (RNE)
__device__ __forceinline__ unsigned pk2(float a, float b){
  union { _Float16 h[2]; unsigned u; } x;
  x.h[0] = (_Float16)a; x.h[1] = (_Float16)b; return x.u;
}
// split 2 floats into fp16 (hi, lo) pairs
__device__ __forceinline__ void pksplit(float a, float b, unsigned& hi, unsigned& lo){
  _Float16 ha = (_Float16)a, hb = (_Float16)b;
  float ra = a - (float)ha, rb = b - (float)hb;
  union { _Float16 h[2]; unsigned u; } x;
  x.h[0] = ha; x.h[1] = hb; hi = x.u;
  x.h[0] = (_Float16)ra; x.h[1] = (_Float16)rb; lo = x.u;
}

// LDS plane offsets (u32 units); row stride 36 u32 (= 72 fp16), 32 rows
#define PLN 1152          // 32*36
#define QH 0
#define QL (1*PLN)
#define KH (2*PLN)
#define KL (3*PLN)
#define VV (4*PLN)

// ---------------------------------------------------------------------------
// K1: dwconv(q,k,v) + fp16-split MFMA gram partials + norm partials.
// V transposed via LDS, stored single-fp16 PRE-PACKED in k3 B-frag order.
// block = (b,head) x 4-row slab (R8: was 8 — grid 768=3 blocks/CU was the
// occupancy wall; 1536 blocks = 6/CU so stalls overlap across blocks).
// NOTE: plain launch_bounds — (256,4) capped VGPR at 64 and spilled (R6).
// ---------------------------------------------------------------------------
__global__ __launch_bounds__(256) void k1_conv_gram(
    const float* __restrict__ x,
    const float* __restrict__ wq, const float* __restrict__ bq,
    const float* __restrict__ wk, const float* __restrict__ bk,
    const float* __restrict__ wv, const float* __restrict__ bv,
    ushort_t* __restrict__ vout,
    float* __restrict__ qn, float* __restrict__ kn,
    float* __restrict__ attn)
{
  __shared__ unsigned sm[5*PLN];   // 23040 B
  const int t  = threadIdx.x;
  const int b  = blockIdx.x / HEADS;
  const int h  = blockIdx.x % HEADS;
  const int r0 = blockIdx.y * 4;
  const int c  = t >> 3;           // channel 0..31
  const int s  = t & 7;            // 8-px strip within half
  const int cg = h*CHH + c;
  const float* xplane = x + (size_t)(b*NC + cg)*NHW;

  float wqr[9], wkr[9], wvr[9];
#pragma unroll
  for (int m = 0; m < 9; ++m) {
    wqr[m] = wq[cg*9+m]; wkr[m] = wk[cg*9+m]; wvr[m] = wv[cg*9+m];
  }
  const float bqv = bq[cg], bkv = bk[cg], bvv = bv[cg];

  const int lane = t & 63;
  const int wid  = t >> 6;         // wave id
  const int gsel = lane >> 4, l15 = lane & 15;
  const int oct  = wid;            // transpose: this wave's channel octet

  floatx4 acc[2][2];
#pragma unroll
  for (int mt = 0; mt < 2; ++mt)
#pragma unroll
    for (int nt = 0; nt < 2; ++nt) acc[mt][nt] = (floatx4){0.f,0.f,0.f,0.f};
  float qnacc = 0.f, knacc = 0.f;

  for (int r = r0; r < r0 + 4; ++r) {
#pragma unroll
    for (int half = 0; half < 2; ++half) {
      const int px0 = half*64 + s*8;
      // ---- conv: 8 px ----
      float xr[3][10];
#pragma unroll
      for (int dr = 0; dr < 3; ++dr) {
        const int rr = r - 1 + dr;
        if (rr >= 0 && rr < IMH) {
          const float* rp = xplane + rr*IMW;
          xr[dr][0] = (px0 > 0) ? rp[px0-1] : 0.f;
          const float4 f0 = *(const float4*)(rp + px0);
          const float4 f1 = *(const float4*)(rp + px0 + 4);
          xr[dr][1]=f0.x; xr[dr][2]=f0.y; xr[dr][3]=f0.z; xr[dr][4]=f0.w;
          xr[dr][5]=f1.x; xr[dr][6]=f1.y; xr[dr][7]=f1.z; xr[dr][8]=f1.w;
          xr[dr][9] = (px0 + 8 < IMW) ? rp[px0+8] : 0.f;
        } else {
#pragma unroll
          for (int j = 0; j < 10; ++j) xr[dr][j] = 0.f;
        }
      }
      float qv[8], kv[8], vv8[8];
#pragma unroll
      for (int p = 0; p < 8; ++p) {
        float qa = bqv, ka = bkv, va = bvv;
#pragma unroll
        for (int dy = 0; dy < 3; ++dy)
#pragma unroll
          for (int dx = 0; dx < 3; ++dx) {
            const float xv = xr[dy][p+dx];
            qa = fmaf(wqr[dy*3+dx], xv, qa);
            ka = fmaf(wkr[dy*3+dx], xv, ka);
            va = fmaf(wvr[dy*3+dx], xv, va);
          }
        qnacc = fmaf(qa, qa, qnacc);
        knacc = fmaf(ka, ka, knacc);
        qv[p] = qa; kv[p] = ka; vv8[p] = va;
      }
      // ---- split/pack -> LDS (row c, u32 cols s*4..s*4+3) ----
      unsigned qhp[4], qlp[4], khp[4], klp[4], vvp[4];
#pragma unroll
      for (int j = 0; j < 4; ++j) {
        pksplit(qv[2*j], qv[2*j+1], qhp[j], qlp[j]);
        pksplit(kv[2*j], kv[2*j+1], khp[j], klp[j]);
        vvp[j] = pk2(vv8[2*j], vv8[2*j+1]);
      }
      const int wb = c*36 + s*4;
      *(uint4*)&sm[QH + wb] = make_uint4(qhp[0],qhp[1],qhp[2],qhp[3]);
      *(uint4*)&sm[QL + wb] = make_uint4(qlp[0],qlp[1],qlp[2],qlp[3]);
      *(uint4*)&sm[KH + wb] = make_uint4(khp[0],khp[1],khp[2],khp[3]);
      *(uint4*)&sm[KL + wb] = make_uint4(klp[0],klp[1],klp[2],klp[3]);
      *(uint4*)&sm[VV + wb] = make_uint4(vvp[0],vvp[1],vvp[2],vvp[3]);
      __syncthreads();

      // ---- v transpose: wave=oct, px=lane; pack channel pairs ----
      {
        const int px = lane;
        const int ph = px >> 1, sel = (px & 1) * 16;
        unsigned w4[4];
#pragma unroll
        for (int i2 = 0; i2 < 4; ++i2) {
          const unsigned ua = sm[VV + (oct*8 + 2*i2    )*36 + ph];
          const unsigned ub = sm[VV + (oct*8 + 2*i2 + 1)*36 + ph];
          w4[i2] = ((ua >> sel) & 0xffffu) | (((ub >> sel) & 0xffffu) << 16);
        }
        const size_t tile = ((size_t)b*1024 + (size_t)r*8 + half*4 + (px>>4))*6 + h;
        ushort_t* dst = vout + tile*512 + (size_t)(oct*16 + (px&15))*8;
        *(uint4*)dst = make_uint4(w4[0],w4[1],w4[2],w4[3]);
      }
      // ---- gram: waves {0,1}<->half0, {2,3}<->half1; K=32 MFMA, zero VALU ----
      if ((wid >> 1) == half) {
        const int col = (wid & 1)*16 + gsel*4;
        half8 aqh[2], aql[2], akh[2], akl[2];
#pragma unroll
        for (int mt = 0; mt < 2; ++mt) {
          const int row = (mt*16 + l15)*36 + col;
          aqh[mt] = *(const half8*)&sm[QH + row];
          aql[mt] = *(const half8*)&sm[QL + row];
          akh[mt] = *(const half8*)&sm[KH + row];
          akl[mt] = *(const half8*)&sm[KL + row];
        }
#pragma unroll
        for (int mt = 0; mt < 2; ++mt)
#pragma unroll
          for (int nt = 0; nt < 2; ++nt) {
            acc[mt][nt] = MFMA_F16(aqh[mt], akh[nt], acc[mt][nt]);
            acc[mt][nt] = MFMA_F16(aqh[mt], akl[nt], acc[mt][nt]);
            acc[mt][nt] = MFMA_F16(aql[mt], akh[nt], acc[mt][nt]);
          }
      }
      __syncthreads();
    }
  }

  // ---- norm partials (8 strip lanes contiguous) ----
  qnacc += __shfl_xor(qnacc, 1); qnacc += __shfl_xor(qnacc, 2); qnacc += __shfl_xor(qnacc, 4);
  knacc += __shfl_xor(knacc, 1); knacc += __shfl_xor(knacc, 2); knacc += __shfl_xor(knacc, 4);
  if (s == 0) {
    atomicAdd(qn + b*NC + cg, qnacc);
    atomicAdd(kn + b*NC + cg, knacc);
  }

  // ---- gram partials: 4-wave LDS reduce, then atomics ----
  float* red = (float*)sm;   // 16 KB <= 23 KB
#pragma unroll
  for (int mt = 0; mt < 2; ++mt)
#pragma unroll
    for (int nt = 0; nt < 2; ++nt)
#pragma unroll
      for (int rg = 0; rg < 4; ++rg)
        red[wid*1024 + (mt*2+nt)*256 + lane*4 + rg] = acc[mt][nt][rg];
  __syncthreads();
  float* abuf = attn + (b*HEADS + h)*(CHH*CHH);
#pragma unroll
  for (int e = 0; e < 4; ++e) {
    const int idx = e*256 + t;
    const float sum = red[idx] + red[1024+idx] + red[2048+idx] + red[3072+idx];
    const int tile = idx >> 8;
    const int ln   = (idx >> 2) & 63;
    const int rg   = idx & 3;
    const int cc   = (tile>>1)*16 + (ln>>4)*4 + rg;
    const int dd   = (tile&1)*16 + (ln & 15);
    atomicAdd(abuf + cc*CHH + dd, sum);
  }
}

// ---------------------------------------------------------------------------
// K2: normalize, softmax, fold projection; M pre-packed fp16 hi/lo A-frags.
// ---------------------------------------------------------------------------
__global__ __launch_bounds__(256) void k2_softmax_M(
    const float* __restrict__ wp,
    const float* __restrict__ qn, const float* __restrict__ kn,
    const float* __restrict__ attn,
    half8* __restrict__ mhi, half8* __restrict__ mlo)
{
  __shared__ float a[CHH][CHH+1];
  __shared__ float qs[CHH], ks_[CHH];
  const int t = threadIdx.x;
  const int b = blockIdx.x / HEADS;
  const int h = blockIdx.x % HEADS;
  const float* raw = attn + (b*HEADS + h)*(CHH*CHH);
  if (t < CHH) {
    qs[t]  = fmaxf(sqrtf(qn[b*NC + h*CHH + t]), EPSN);
    ks_[t] = fmaxf(sqrtf(kn[b*NC + h*CHH + t]), EPSN);
  }
  __syncthreads();
#pragma unroll
  for (int rep = 0; rep < 4; ++rep) {
    const int idx = rep*256 + t;
    const int cc = idx >> 5, dd = idx & 31;
    a[cc][dd] = raw[idx] / (qs[cc] * ks_[dd]);
  }
  __syncthreads();
  if (t < CHH) {
    float m = -1e30f;
    for (int d = 0; d < CHH; ++d) m = fmaxf(m, a[t][d]);
    float sum = 0.f;
    for (int d = 0; d < CHH; ++d) { const float e = expf(a[t][d] - m); a[t][d] = e; sum += e; }
    const float inv = 1.f / sum;
    for (int d = 0; d < CHH; ++d) a[t][d] *= inv;
  }
  __syncthreads();
#pragma unroll
  for (int rep = 0; rep < 3; ++rep) {
    const int slot = rep*256 + t;
    const int o = slot >> 2;
    const int g = slot & 3;
    float m[8];
#pragma unroll
    for (int i = 0; i < 8; ++i) m[i] = 0.f;
    for (int cp = 0; cp < CHH; ++cp) {
      const float w = wp[o*NC + h*CHH + cp];
#pragma unroll
      for (int i = 0; i < 8; ++i) m[i] = fmaf(w, a[cp][g*8+i], m[i]);
    }
    half8 hi8, lo8;
#pragma unroll
    for (int i = 0; i < 8; ++i) {
      const _Float16 hh = (_Float16)m[i];
      hi8[i] = hh;
      lo8[i] = (_Float16)(m[i] - (float)hh);
    }
    const size_t mi = (((size_t)b*12 + (o>>4))*6 + h)*64 + g*16 + (o&15);
    mhi[mi] = hi8; mlo[mi] = lo8;
  }
}

// ---------------------------------------------------------------------------
// K3: out = M·V + bp. fp16 MFMA, 2-product (Mhi+Mlo)·V. All frags coalesced.
// block = 128 px x 192 o; wave = 64 px (4 tiles) x 96 o (6 tiles).
// ---------------------------------------------------------------------------
__global__ __launch_bounds__(256) void k3_gemm(
    const half8* __restrict__ v,
    const half8* __restrict__ mhi, const half8* __restrict__ mlo,
    const float* __restrict__ bp, float* __restrict__ out)
{
  const int t    = threadIdx.x;
  const int b    = blockIdx.y;
  const int lane = t & 63;
  const int w    = t >> 6;
  const int whw  = w & 1;
  const int wo   = w >> 1;
  const int ht0  = blockIdx.x*8 + whw*4;
  const int ot0  = wo*6;
  const int gsel = lane >> 4, l15 = lane & 15;

  floatx4 acc[6][4];
#pragma unroll
  for (int ot = 0; ot < 6; ++ot)
#pragma unroll
    for (int nt = 0; nt < 4; ++nt) acc[ot][nt] = (floatx4){0.f,0.f,0.f,0.f};

  const size_t vbase = ((size_t)b*1024 + ht0)*6;
  const size_t mbase = ((size_t)b*12 + ot0)*6;
#pragma unroll
  for (int ks = 0; ks < 6; ++ks) {
    half8 bf[4];
#pragma unroll
    for (int nt = 0; nt < 4; ++nt)
      bf[nt] = v[(vbase + (size_t)nt*6 + ks)*64 + lane];
#pragma unroll
    for (int ot = 0; ot < 6; ++ot) {
      const size_t mi = (mbase + (size_t)ot*6 + ks)*64 + lane;
      const half8 ah = mhi[mi];
      const half8 al = mlo[mi];
#pragma unroll
      for (int nt = 0; nt < 4; ++nt) {
        acc[ot][nt] = MFMA_F16(ah, bf[nt], acc[ot][nt]);
        acc[ot][nt] = MFMA_F16(al, bf[nt], acc[ot][nt]);
      }
    }
  }
#pragma unroll
  for (int ot = 0; ot < 6; ++ot) {
#pragma unroll
    for (int rg = 0; rg < 4; ++rg) {
      const int o = (ot0 + ot)*16 + gsel*4 + rg;
      const float bpv = bp[o];
#pragma unroll
      for (int nt = 0; nt < 4; ++nt) {
        const int hw = (ht0 + nt)*16 + l15;
        out[((size_t)(b*NC + o))*NHW + hw] = acc[ot][nt][rg] + bpv;
      }
    }
  }
}

extern "C" void kernel_launch(void* const* d_in, const int* in_sizes, int n_in,
                              void* d_out, int out_size, void* d_ws, size_t ws_size,
                              hipStream_t stream)
{
  const float* x  = (const float*)d_in[0];
  const float* wq = (const float*)d_in[1];
  const float* bq = (const float*)d_in[2];
  const float* wk = (const float*)d_in[3];
  const float* bk = (const float*)d_in[4];
  const float* wv = (const float*)d_in[5];
  const float* bv = (const float*)d_in[6];
  const float* wp = (const float*)d_in[7];
  const float* bp = (const float*)d_in[8];
  float* out = (float*)d_out;

  // workspace layout
  ushort_t* vout = (ushort_t*)d_ws;                       // fp16 V frags
  float* fbase   = (float*)(vout + (size_t)NBCHW);
  float* qn      = fbase;
  float* kn      = qn + NB*NC;
  float* attn    = kn + NB*NC;
  half8* mhi     = (half8*)(attn + NB*HEADS*CHH*CHH);
  half8* mlo     = mhi + (size_t)NB*12*6*64;

  hipMemsetAsync(fbase, 0,
                 (size_t)(2*NB*NC + NB*HEADS*CHH*CHH)*sizeof(float), stream);

  k1_conv_gram<<<dim3(NB*HEADS, 32), 256, 0, stream>>>(
      x, wq, bq, wk, bk, wv, bv, vout, qn, kn, attn);
  k2_softmax_M<<<NB*HEADS, 256, 0, stream>>>(wp, qn, kn, attn, mhi, mlo);
  k3_gemm<<<dim3(NHW/128, NB), 256, 0, stream>>>(
      (const half8*)vout, mhi, mlo, bp, out);
}